// Round 9
// baseline (5087.416 us; speedup 1.0000x reference)
//
#include <hip/hip_runtime.h>
#include <hip/hip_bf16.h>

// TTAGN: LSTM(edge,node) -> GAT x2 + GCN x2 -> classifier.
// Inputs fp32, internal fp32, OUTPUT fp32.
// d_out = concat(out[N,4], x_gcn[N,64], x_gat[N,64]) as fp32.
// Scratch in __device__ globals.
//
// R9: (a) LSTM 128-thread blocks (r8 regression: 2seq/thread @256 threads
//     halved grid to 3 blk/CU, occ 21%, VALU 67%); (b) CSR gather replaces
//     ALL E*64 fp32 scatter atomics (4 kernels), folds bias/norm/lrelu/fin
//     epilogues in, and replaces per-element division by per-node rcp.

typedef unsigned int u32;

#define NN 50000
#define EE 400000

__device__ float g_nodeF[NN * 16];
__device__ float g_esc[EE];
__device__ float g_P1[NN * 64];
__device__ float g_P2[NN * 64];
__device__ float g_alpha[NN * 8];
__device__ float g_amax[NN * 8];
__device__ float g_rinv[NN * 8];
__device__ float g_dinv[NN];
__device__ int   g_cnt[NN];
__device__ int   g_rs[NN + 1];
__device__ int   g_cur[NN];
__device__ int   g_csrc[EE];
__device__ float g_cesc[EE];

__device__ __forceinline__ float rcpf(float x) { return __builtin_amdgcn_rcpf(x); }
__device__ __forceinline__ float sigf(float x) { return rcpf(1.0f + __expf(-x)); }
__device__ __forceinline__ float tanh_fast(float x) {
    return 1.0f - 2.0f * rcpf(__expf(2.0f * x) + 1.0f);
}

// ---------------- LSTM ----------------
// One step for TWO sequences; each LDS weight broadcast feeds 2 FMA chains.
__device__ __forceinline__ void lstm_step2(
    float x00, float x01, float x10, float x11,
    float* __restrict__ h0, float* __restrict__ c0,
    float* __restrict__ h1, float* __restrict__ c1,
    const float* __restrict__ sWih, const float* __restrict__ sWhh,
    const float* __restrict__ sB)
{
    float hn0[16], hn1[16];
#pragma unroll 2
    for (int u = 0; u < 16; ++u) {
        float bi = sB[u], bf = sB[u + 16], bg = sB[u + 32], bo = sB[u + 48];
        float wi0 = sWih[2 * u],      wi1 = sWih[2 * u + 1];
        float wf0 = sWih[2 * u + 32], wf1 = sWih[2 * u + 33];
        float wg0 = sWih[2 * u + 64], wg1 = sWih[2 * u + 65];
        float wo0 = sWih[2 * u + 96], wo1 = sWih[2 * u + 97];
        float ip0 = bi + wi0 * x00 + wi1 * x01, ip1 = bi + wi0 * x10 + wi1 * x11;
        float fp0 = bf + wf0 * x00 + wf1 * x01, fp1 = bf + wf0 * x10 + wf1 * x11;
        float gp0 = bg + wg0 * x00 + wg1 * x01, gp1 = bg + wg0 * x10 + wg1 * x11;
        float op0 = bo + wo0 * x00 + wo1 * x01, op1 = bo + wo0 * x10 + wo1 * x11;
#pragma unroll
        for (int k = 0; k < 16; ++k) {
            float wI = sWhh[u * 16 + k];
            float wF = sWhh[(u + 16) * 16 + k];
            float wG = sWhh[(u + 32) * 16 + k];
            float wO = sWhh[(u + 48) * 16 + k];
            float h0k = h0[k], h1k = h1[k];
            ip0 += wI * h0k; ip1 += wI * h1k;
            fp0 += wF * h0k; fp1 += wF * h1k;
            gp0 += wG * h0k; gp1 += wG * h1k;
            op0 += wO * h0k; op1 += wO * h1k;
        }
        float cu0 = sigf(fp0) * c0[u] + sigf(ip0) * tanh_fast(gp0);
        float cu1 = sigf(fp1) * c1[u] + sigf(ip1) * tanh_fast(gp1);
        c0[u] = cu0; c1[u] = cu1;
        hn0[u] = sigf(op0) * tanh_fast(cu0);
        hn1[u] = sigf(op1) * tanh_fast(cu1);
    }
#pragma unroll
    for (int u = 0; u < 16; ++u) { h0[u] = hn0[u]; h1[u] = hn1[u]; }
}

template <bool EDGE>
__device__ __forceinline__ void lstm_emit(
    const float* __restrict__ h, const float* __restrict__ sD,
    float* __restrict__ outp, int e)
{
    if (EDGE) {
        float s = sD[16];
#pragma unroll
        for (int u = 0; u < 16; ++u) s += h[u] * sD[u];
        outp[e] = s;
    } else {
        float* dst = outp + (size_t)e * 16;
#pragma unroll
        for (int q = 0; q < 4; ++q)
            *(float4*)(dst + q * 4) = make_float4(h[4 * q], h[4 * q + 1], h[4 * q + 2], h[4 * q + 3]);
    }
}

// 128 threads/block, 2 sequences/thread -> grid = B/256 (6+ blocks/CU at E).
template <bool EDGE>
__global__ void __launch_bounds__(128, 5) lstm_kernel(
    const float* __restrict__ seq, const int* __restrict__ lens,
    const float* __restrict__ Wih, const float* __restrict__ Whh,
    const float* __restrict__ bias,
    const float* __restrict__ dnnW, const float* __restrict__ dnnb,
    float* __restrict__ outp, int B)
{
    __shared__ float sWih[128];
    __shared__ float sWhh[1024];
    __shared__ float sB[64];
    __shared__ float sD[17];
    int tid = threadIdx.x;
    if (tid < 128) sWih[tid] = Wih[tid];
    for (int i = tid; i < 1024; i += 128) sWhh[i] = Whh[i];
    if (tid < 64) sB[tid] = bias[tid];
    if (EDGE) {
        if (tid < 16) sD[tid] = dnnW[tid];
        if (tid == 16) sD[16] = dnnb[0];
    }
    __syncthreads();
    int e0 = blockIdx.x * 256 + tid;     // seq A
    int e1 = e0 + 128;                   // seq B
    if (e0 >= B) return;
    bool v1 = e1 < B;
    int e1c = v1 ? e1 : e0;              // clamp loads; stores guarded

    const float4* sp0 = (const float4*)seq + (size_t)e0 * 8;   // 32 floats/seq
    const float4* sp1 = (const float4*)seq + (size_t)e1c * 8;
    int l0 = lens[e0] - 1;               // in [0,15]
    int l1 = lens[e1c] - 1;
    float h0[16], c0[16], h1[16], c1[16];
#pragma unroll
    for (int u = 0; u < 16; ++u) { h0[u] = 0.f; c0[u] = 0.f; h1[u] = 0.f; c1[u] = 0.f; }

    float4 q0 = sp0[0];
    float4 q1 = sp1[0];
#pragma unroll 1
    for (int i = 0; i < 8; ++i) {
        float4 n0 = sp0[(i + 1) & 7];    // prefetch (wraps on last iter; in-bounds)
        float4 n1 = sp1[(i + 1) & 7];
        lstm_step2(q0.x, q0.y, q1.x, q1.y, h0, c0, h1, c1, sWih, sWhh, sB);
        if (2 * i == l0)        lstm_emit<EDGE>(h0, sD, outp, e0);
        if (v1 && 2 * i == l1)  lstm_emit<EDGE>(h1, sD, outp, e1);
        lstm_step2(q0.z, q0.w, q1.z, q1.w, h0, c0, h1, c1, sWih, sWhh, sB);
        if (2 * i + 1 == l0)       lstm_emit<EDGE>(h0, sD, outp, e0);
        if (v1 && 2 * i + 1 == l1) lstm_emit<EDGE>(h1, sD, outp, e1);
        q0 = n0; q1 = n1;
    }
}

// ---------------- CSR build ----------------
__global__ void __launch_bounds__(256) zero_cnt_kernel(int* cnt, int n)
{
    int t = blockIdx.x * 256 + threadIdx.x;
    if (t < n) cnt[t] = 0;
}
__global__ void __launch_bounds__(256) count_kernel(const int* __restrict__ dst,
                                                    int* cnt, int E)
{
    int e = blockIdx.x * 256 + threadIdx.x;
    if (e < E) atomicAdd(&cnt[dst[e]], 1);
}
// single-block exclusive scan; also rowstart[n]=E and cursor copy.
__global__ void __launch_bounds__(256) scan_kernel(const int* __restrict__ cnt,
                                                   int* __restrict__ rs,
                                                   int* __restrict__ cur,
                                                   int n, int E)
{
    __shared__ int part[256];
    int t = threadIdx.x;
    const int CH = (n + 255) / 256;
    int base = t * CH;
    int s = 0;
    for (int i = 0; i < CH; ++i) {
        int idx = base + i;
        if (idx < n) s += cnt[idx];
    }
    part[t] = s;
    __syncthreads();
    if (t == 0) {
        int acc = 0;
        for (int i = 0; i < 256; ++i) { int v = part[i]; part[i] = acc; acc += v; }
    }
    __syncthreads();
    int run = part[t];
    for (int i = 0; i < CH; ++i) {
        int idx = base + i;
        if (idx < n) { rs[idx] = run; cur[idx] = run; run += cnt[idx]; }
    }
    if (t == 0) rs[n] = E;
}
__global__ void __launch_bounds__(256) fill_kernel(const int* __restrict__ src,
                                                   const int* __restrict__ dst,
                                                   const float* __restrict__ esc,
                                                   int* __restrict__ cur,
                                                   int* __restrict__ csrc,
                                                   float* __restrict__ cesc, int E)
{
    int e = blockIdx.x * 256 + threadIdx.x;
    if (e >= E) return;
    int pos = atomicAdd(&cur[dst[e]], 1);
    csrc[pos] = src[e];
    cesc[pos] = esc[e];
}
__global__ void __launch_bounds__(256) dinv_kernel(const int* __restrict__ cnt,
                                                   float* __restrict__ dinv, int n)
{
    int t = blockIdx.x * 256 + threadIdx.x;
    if (t < n) dinv[t] = rsqrtf((float)cnt[t] + 1.0f);
}

// --- C[n,64] = [x(240)|nodeF(16)] @ W[256,64]; 32KB static LDS, 2-phase K ---
__global__ void __launch_bounds__(256) gemmX_kernel(
    const float* __restrict__ x, const float* __restrict__ nodeF,
    const float* __restrict__ W, float* __restrict__ C, int n)
{
    __shared__ float sW[128 * 64];  // 32 KB
    int j = threadIdx.x & 63;
    int node = blockIdx.x * 4 + (threadIdx.x >> 6);
    bool valid = node < n;
    const float4* xr = (const float4*)(x + (size_t)node * 240);
    float acc = 0.f;

    for (int i = threadIdx.x; i < 128 * 64; i += 256) sW[i] = W[i];
    __syncthreads();
    if (valid) {
#pragma unroll 4
        for (int k4 = 0; k4 < 32; ++k4) {
            float4 v = xr[k4];
            const float* wr = sW + k4 * 256 + j;
            acc += v.x * wr[0] + v.y * wr[64] + v.z * wr[128] + v.w * wr[192];
        }
    }
    __syncthreads();
    for (int i = threadIdx.x; i < 128 * 64; i += 256) sW[i] = W[128 * 64 + i];
    __syncthreads();
    if (valid) {
#pragma unroll 4
        for (int k4 = 32; k4 < 60; ++k4) {
            float4 v = xr[k4];
            const float* wr = sW + (k4 - 32) * 256 + j;
            acc += v.x * wr[0] + v.y * wr[64] + v.z * wr[128] + v.w * wr[192];
        }
        const float4* nf = (const float4*)(nodeF + (size_t)node * 16);
#pragma unroll
        for (int k4 = 60; k4 < 64; ++k4) {
            float4 v = nf[k4 - 60];
            const float* wr = sW + (k4 - 32) * 256 + j;
            acc += v.x * wr[0] + v.y * wr[64] + v.z * wr[128] + v.w * wr[192];
        }
        C[(size_t)node * 64 + j] = acc;
    }
}

// ------- C[n,64] = A[n,64] @ W[64,64]; 16KB static LDS -------
__global__ void __launch_bounds__(256) gemm64_kernel(const float* __restrict__ A,
                                                     const float* __restrict__ W,
                                                     float* __restrict__ C, int n)
{
    __shared__ float sW[64 * 64];  // 16 KB
    for (int i = threadIdx.x; i < 64 * 64; i += 256) sW[i] = W[i];
    __syncthreads();
    int j = threadIdx.x & 63;
    int node = blockIdx.x * 4 + (threadIdx.x >> 6);
    if (node >= n) return;
    const float4* a4 = (const float4*)(A + (size_t)node * 64);
    float acc = 0.f;
#pragma unroll 4
    for (int k4 = 0; k4 < 16; ++k4) {
        float4 v = a4[k4];
        const float* wr = sW + k4 * 256 + j;
        acc += v.x * wr[0] + v.y * wr[64] + v.z * wr[128] + v.w * wr[192];
    }
    C[(size_t)node * 64 + j] = acc;
}

// ---------------- GAT ----------------
template <int H, int C>
__global__ void __launch_bounds__(256) alpha_kernel(const float* __restrict__ xh,
                                                    const float* __restrict__ att,
                                                    float* __restrict__ alpha, int n)
{
    int t = blockIdx.x * 256 + threadIdx.x;
    if (t >= n * H) return;
    int h = (H == 1) ? 0 : (t % H);
    int nd = (H == 1) ? t : (t / H);
    const float* row = xh + (size_t)nd * 64 + h * C;
    float s = 0.f;
#pragma unroll
    for (int c = 0; c < C; ++c) s += row[c] * att[h * C + c];
    alpha[t] = s;
}

// per (dst,h): max then sum over in-edges (CSR). Writes amax, rinv=1/sum.
template <int H>
__global__ void __launch_bounds__(256) gat_softmax_csr_kernel(
    const int* __restrict__ rs, const int* __restrict__ csrc,
    const float* __restrict__ alpha,
    float* __restrict__ amax, float* __restrict__ rinv, int n)
{
    int t = blockIdx.x * 256 + threadIdx.x;
    if (t >= n * H) return;
    int h = (H == 1) ? 0 : (t % H);
    int d = (H == 1) ? t : (t / H);
    int k0 = rs[d], k1 = rs[d + 1];
    float m = -INFINITY;
    for (int k = k0; k < k1; ++k) {
        float a = alpha[(size_t)csrc[k] * H + h];
        a = a > 0.f ? a : 0.2f * a;
        m = fmaxf(m, a);
    }
    float s = 0.f;
    for (int k = k0; k < k1; ++k) {
        float a = alpha[(size_t)csrc[k] * H + h];
        a = a > 0.f ? a : 0.2f * a;
        s += __expf(a - m);
    }
    amax[t] = m;
    rinv[t] = rcpf(s);
}

// one wave per dst node (lane = feature col). acc = xh[d]+bias + sum coef*xh[s].
// FILTER: apply isfinite->0 (GAT2 output).
template <int H, bool FILTER>
__global__ void __launch_bounds__(256) gat_gather_kernel(
    const int* __restrict__ rs, const int* __restrict__ csrc,
    const float* __restrict__ cesc,
    const float* __restrict__ xh, const float* __restrict__ alpha,
    const float* __restrict__ amax, const float* __restrict__ rinv,
    const float* __restrict__ bias, float* __restrict__ out, int n)
{
    int j = threadIdx.x & 63;
    int d = blockIdx.x * 4 + (threadIdx.x >> 6);
    if (d >= n) return;
    int h = (H == 8) ? (j >> 3) : 0;
    float m = amax[(size_t)d * H + h];
    float ri = rinv[(size_t)d * H + h];
    float acc = xh[(size_t)d * 64 + j] + bias[j];
    int k1 = rs[d + 1];
#pragma unroll 2
    for (int k = rs[d]; k < k1; ++k) {
        int s = csrc[k];
        float a = alpha[(size_t)s * H + h];
        a = a > 0.f ? a : 0.2f * a;
        float coef = __expf(a - m) * ri + cesc[k];
        acc += xh[(size_t)s * 64 + j] * coef;
    }
    if (FILTER && !__builtin_isfinite(acc)) acc = 0.f;
    out[(size_t)d * 64 + j] = acc;
}

// ---------------- GCN gather (norm + bias + leaky_relu fused) ----------------
__global__ void __launch_bounds__(256) gcn_gather_kernel(
    const int* __restrict__ rs, const int* __restrict__ csrc,
    const float* __restrict__ xw, const float* __restrict__ dinv,
    const float* __restrict__ bias, float* __restrict__ out, int n)
{
    int j = threadIdx.x & 63;
    int d = blockIdx.x * 4 + (threadIdx.x >> 6);
    if (d >= n) return;
    float di = dinv[d];
    float acc = xw[(size_t)d * 64 + j] * di * di + bias[j];
    int k1 = rs[d + 1];
#pragma unroll 2
    for (int k = rs[d]; k < k1; ++k) {
        int s = csrc[k];
        acc += xw[(size_t)s * 64 + j] * (dinv[s] * di);
    }
    out[(size_t)d * 64 + j] = acc > 0.f ? acc : 0.01f * acc;  // leaky_relu(0.01)
}

// ---------------- classifier (fused 320->32->16->4; 43.5KB static LDS) ---------
__global__ void __launch_bounds__(256) cls_kernel(
    const float* __restrict__ x, const float* __restrict__ nodeF,
    const float* __restrict__ xg,
    const float* __restrict__ W1, const float* __restrict__ b1,
    const float* __restrict__ W2, const float* __restrict__ b2,
    const float* __restrict__ W3, const float* __restrict__ b3,
    float* __restrict__ outp, int n)
{
    __shared__ float sW1[320 * 32];
    __shared__ float sW2[32 * 16];
    __shared__ float sW3[16 * 4];
    __shared__ float sb1[32], sb2[16], sb3[4];
    int tid = threadIdx.x;
    for (int i = tid; i < 320 * 32; i += 256) sW1[i] = W1[i];
    for (int i = tid; i < 512; i += 256) sW2[i] = W2[i];
    if (tid < 64) sW3[tid] = W3[tid];
    if (tid < 32) sb1[tid] = b1[tid];
    if (tid < 16) sb2[tid] = b2[tid];
    if (tid < 4)  sb3[tid] = b3[tid];
    __syncthreads();
    int nd = blockIdx.x * 256 + tid;
    if (nd >= n) return;

    float a1[32];
#pragma unroll
    for (int j = 0; j < 32; ++j) a1[j] = sb1[j];
    const float4* xr = (const float4*)(x + (size_t)nd * 240);
#pragma unroll 1
    for (int k4 = 0; k4 < 60; ++k4) {
        float4 v = xr[k4];
        const float* wr = sW1 + k4 * 128;
#pragma unroll
        for (int j = 0; j < 32; ++j)
            a1[j] += v.x * wr[j] + v.y * wr[32 + j] + v.z * wr[64 + j] + v.w * wr[96 + j];
    }
    const float4* nf = (const float4*)(nodeF + (size_t)nd * 16);
#pragma unroll 1
    for (int k4 = 60; k4 < 64; ++k4) {
        float4 v = nf[k4 - 60];
        const float* wr = sW1 + k4 * 128;
#pragma unroll
        for (int j = 0; j < 32; ++j)
            a1[j] += v.x * wr[j] + v.y * wr[32 + j] + v.z * wr[64 + j] + v.w * wr[96 + j];
    }
    const float4* p2 = (const float4*)(xg + (size_t)nd * 64);
#pragma unroll 1
    for (int k4 = 0; k4 < 16; ++k4) {
        float4 v = p2[k4];
        const float* wr = sW1 + 8192 + k4 * 128;  // rows 256 + 4*k4
#pragma unroll
        for (int j = 0; j < 32; ++j)
            a1[j] += v.x * wr[j] + v.y * wr[32 + j] + v.z * wr[64 + j] + v.w * wr[96 + j];
    }
#pragma unroll
    for (int j = 0; j < 32; ++j) { float v = a1[j]; a1[j] = v > 0.f ? v : 0.01f * v; }

    float a2[16];
#pragma unroll
    for (int j = 0; j < 16; ++j) a2[j] = sb2[j];
#pragma unroll
    for (int k = 0; k < 32; ++k) {
        float v = a1[k];
        const float* wr = sW2 + k * 16;
#pragma unroll
        for (int j = 0; j < 16; ++j) a2[j] += v * wr[j];
    }
#pragma unroll
    for (int j = 0; j < 16; ++j) { float v = a2[j]; a2[j] = v > 0.f ? v : 0.01f * v; }

    float a3[4] = {sb3[0], sb3[1], sb3[2], sb3[3]};
#pragma unroll
    for (int k = 0; k < 16; ++k) {
        float v = a2[k];
        const float* wr = sW3 + k * 4;
        a3[0] += v * wr[0]; a3[1] += v * wr[1]; a3[2] += v * wr[2]; a3[3] += v * wr[3];
    }
    float4 o = make_float4(a3[0], a3[1], a3[2], a3[3]);
    *(float4*)(outp + (size_t)nd * 4) = o;
}

// ---------------- launcher ----------------
static inline unsigned nblk(size_t t) { return (unsigned)((t + 255) / 256); }

extern "C" void kernel_launch(void* const* d_in, const int* in_sizes, int n_in,
                              void* d_out, int out_size, void* d_ws, size_t ws_size,
                              hipStream_t stream)
{
    const float* x     = (const float*)d_in[0];
    const float* eseq  = (const float*)d_in[1];
    const float* nseq  = (const float*)d_in[2];
    const float* Wih   = (const float*)d_in[3];
    const float* Whh   = (const float*)d_in[4];
    const float* lb    = (const float*)d_in[5];
    const float* dnnW  = (const float*)d_in[6];
    const float* dnnb  = (const float*)d_in[7];
    const float* g1W   = (const float*)d_in[8];
    const float* g1att = (const float*)d_in[9];
    const float* g1b   = (const float*)d_in[10];
    const float* g2W   = (const float*)d_in[11];
    const float* g2att = (const float*)d_in[12];
    const float* g2b   = (const float*)d_in[13];
    const float* gc1W  = (const float*)d_in[14];
    const float* gc1b  = (const float*)d_in[15];
    const float* gc2W  = (const float*)d_in[16];
    const float* gc2b  = (const float*)d_in[17];
    const float* c1W   = (const float*)d_in[18];
    const float* c1b   = (const float*)d_in[19];
    const float* c2W   = (const float*)d_in[20];
    const float* c2b   = (const float*)d_in[21];
    const float* c3W   = (const float*)d_in[22];
    const float* c3b   = (const float*)d_in[23];
    const int* eidx  = (const int*)d_in[24];
    const int* elen  = (const int*)d_in[25];
    const int* nlen  = (const int*)d_in[26];

    const int N = NN;
    const int E = EE;
    const int* srcp = eidx;
    const int* dstp = eidx + E;

    // device-global scratch
    float *nodeF, *esc, *P1, *P2, *alpha, *amax, *rinv, *dinv, *cesc;
    int *cnt, *rs, *cur, *csrc;
    hipGetSymbolAddress((void**)&nodeF, HIP_SYMBOL(g_nodeF));
    hipGetSymbolAddress((void**)&esc,   HIP_SYMBOL(g_esc));
    hipGetSymbolAddress((void**)&P1,    HIP_SYMBOL(g_P1));
    hipGetSymbolAddress((void**)&P2,    HIP_SYMBOL(g_P2));
    hipGetSymbolAddress((void**)&alpha, HIP_SYMBOL(g_alpha));
    hipGetSymbolAddress((void**)&amax,  HIP_SYMBOL(g_amax));
    hipGetSymbolAddress((void**)&rinv,  HIP_SYMBOL(g_rinv));
    hipGetSymbolAddress((void**)&dinv,  HIP_SYMBOL(g_dinv));
    hipGetSymbolAddress((void**)&cnt,   HIP_SYMBOL(g_cnt));
    hipGetSymbolAddress((void**)&rs,    HIP_SYMBOL(g_rs));
    hipGetSymbolAddress((void**)&cur,   HIP_SYMBOL(g_cur));
    hipGetSymbolAddress((void**)&csrc,  HIP_SYMBOL(g_csrc));
    hipGetSymbolAddress((void**)&cesc,  HIP_SYMBOL(g_cesc));

    float* out0   = (float*)d_out;             // [N,4]
    float* outGcn = out0 + (size_t)N * 4;      // [N,64]
    float* outGat = outGcn + (size_t)N * 64;   // [N,64]

    // ---- temporal branches ----
    lstm_kernel<false><<<(N + 255) / 256, 128, 0, stream>>>(nseq, nlen, Wih, Whh, lb, dnnW, dnnb, nodeF, N);
    lstm_kernel<true><<<(E + 255) / 256, 128, 0, stream>>>(eseq, elen, Wih, Whh, lb, dnnW, dnnb, esc, E);

    // ---- CSR build (graph fixed per launch; also yields GCN degrees) ----
    zero_cnt_kernel<<<nblk(N), 256, 0, stream>>>(cnt, N);
    count_kernel<<<nblk(E), 256, 0, stream>>>(dstp, cnt, E);
    scan_kernel<<<1, 256, 0, stream>>>(cnt, rs, cur, N, E);
    fill_kernel<<<nblk(E), 256, 0, stream>>>(srcp, dstp, esc, cur, csrc, cesc, E);
    dinv_kernel<<<nblk(N), 256, 0, stream>>>(cnt, dinv, N);

    // ---- GAT layer 1 (H=8, C=8): P1 = xh1, P2 = gat1 out ----
    gemmX_kernel<<<(N + 3) / 4, 256, 0, stream>>>(x, nodeF, g1W, P1, N);
    alpha_kernel<8, 8><<<nblk((size_t)N * 8), 256, 0, stream>>>(P1, g1att, alpha, N);
    gat_softmax_csr_kernel<8><<<nblk((size_t)N * 8), 256, 0, stream>>>(rs, csrc, alpha, amax, rinv, N);
    gat_gather_kernel<8, false><<<(N + 3) / 4, 256, 0, stream>>>(
        rs, csrc, cesc, P1, alpha, amax, rinv, g1b, P2, N);

    // ---- GAT layer 2 (H=1, C=64): P1 = xh2, output -> outGat ----
    gemm64_kernel<<<(N + 3) / 4, 256, 0, stream>>>(P2, g2W, P1, N);
    alpha_kernel<1, 64><<<nblk(N), 256, 0, stream>>>(P1, g2att, alpha, N);
    gat_softmax_csr_kernel<1><<<nblk(N), 256, 0, stream>>>(rs, csrc, alpha, amax, rinv, N);
    gat_gather_kernel<1, true><<<(N + 3) / 4, 256, 0, stream>>>(
        rs, csrc, cesc, P1, alpha, amax, rinv, g2b, outGat, N);

    // ---- GCN layer 1: P1 = xw1, P2 = lrelu(gcn1) ----
    gemmX_kernel<<<(N + 3) / 4, 256, 0, stream>>>(x, nodeF, gc1W, P1, N);
    gcn_gather_kernel<<<(N + 3) / 4, 256, 0, stream>>>(rs, csrc, P1, dinv, gc1b, P2, N);

    // ---- GCN layer 2: P1 = xw2, output -> outGcn (x_gcn, lrelu fused) ----
    gemm64_kernel<<<(N + 3) / 4, 256, 0, stream>>>(P2, gc2W, P1, N);
    gcn_gather_kernel<<<(N + 3) / 4, 256, 0, stream>>>(rs, csrc, P1, dinv, gc2b, outGcn, N);

    // ---- classifier (reads x_gcn from d_out) ----
    cls_kernel<<<nblk(N), 256, 0, stream>>>(x, nodeF, outGcn, c1W, c1b, c2W, c2b, c3W, c3b, out0, N);
}

// Round 10
// 1517.251 us; speedup vs baseline: 3.3530x; 3.3530x over previous
//
#include <hip/hip_runtime.h>
#include <hip/hip_bf16.h>

// TTAGN: LSTM(edge,node) -> GAT x2 + GCN x2 -> classifier.
// Inputs fp32, internal fp32, OUTPUT fp32.
// d_out = concat(out[N,4], x_gcn[N,64], x_gat[N,64]) as fp32.
// Scratch in __device__ globals.
//
// R10: revert r9's lstm launch_bounds disaster. (128,5) capped VGPR at ~102,
// allocator compressed to 48 and spilled all h/c state -> 15.5 GB scratch
// traffic, 3.8ms. Now: edge = 2seq/thread @(128,3) (VGPR cap 170, grid 1563);
// node = 1seq/thread @(128,3) (grid 391). CSR gather pipeline unchanged (r9).

typedef unsigned int u32;

#define NN 50000
#define EE 400000

__device__ float g_nodeF[NN * 16];
__device__ float g_esc[EE];
__device__ float g_P1[NN * 64];
__device__ float g_P2[NN * 64];
__device__ float g_alpha[NN * 8];
__device__ float g_amax[NN * 8];
__device__ float g_rinv[NN * 8];
__device__ float g_dinv[NN];
__device__ int   g_cnt[NN];
__device__ int   g_rs[NN + 1];
__device__ int   g_cur[NN];
__device__ int   g_csrc[EE];
__device__ float g_cesc[EE];

__device__ __forceinline__ float rcpf(float x) { return __builtin_amdgcn_rcpf(x); }
__device__ __forceinline__ float sigf(float x) { return rcpf(1.0f + __expf(-x)); }
__device__ __forceinline__ float tanh_fast(float x) {
    return 1.0f - 2.0f * rcpf(__expf(2.0f * x) + 1.0f);
}

// ---------------- LSTM ----------------
__device__ __forceinline__ void lstm_step1(
    float x0, float x1, float* __restrict__ h, float* __restrict__ c,
    const float* __restrict__ sWih, const float* __restrict__ sWhh,
    const float* __restrict__ sB)
{
    float hn[16];
#pragma unroll 4
    for (int u = 0; u < 16; ++u) {
        float ip = sB[u]      + sWih[2 * u]      * x0 + sWih[2 * u + 1]  * x1;
        float fp = sB[u + 16] + sWih[2 * u + 32] * x0 + sWih[2 * u + 33] * x1;
        float gp = sB[u + 32] + sWih[2 * u + 64] * x0 + sWih[2 * u + 65] * x1;
        float op = sB[u + 48] + sWih[2 * u + 96] * x0 + sWih[2 * u + 97] * x1;
#pragma unroll
        for (int k = 0; k < 16; ++k) {
            float hk = h[k];
            ip += sWhh[u * 16 + k]        * hk;
            fp += sWhh[(u + 16) * 16 + k] * hk;
            gp += sWhh[(u + 32) * 16 + k] * hk;
            op += sWhh[(u + 48) * 16 + k] * hk;
        }
        float cu = sigf(fp) * c[u] + sigf(ip) * tanh_fast(gp);
        c[u] = cu;
        hn[u] = sigf(op) * tanh_fast(cu);
    }
#pragma unroll
    for (int u = 0; u < 16; ++u) h[u] = hn[u];
}

// One step for TWO sequences; each LDS weight broadcast feeds 2 FMA chains.
__device__ __forceinline__ void lstm_step2(
    float x00, float x01, float x10, float x11,
    float* __restrict__ h0, float* __restrict__ c0,
    float* __restrict__ h1, float* __restrict__ c1,
    const float* __restrict__ sWih, const float* __restrict__ sWhh,
    const float* __restrict__ sB)
{
    float hn0[16], hn1[16];
#pragma unroll 2
    for (int u = 0; u < 16; ++u) {
        float bi = sB[u], bf = sB[u + 16], bg = sB[u + 32], bo = sB[u + 48];
        float wi0 = sWih[2 * u],      wi1 = sWih[2 * u + 1];
        float wf0 = sWih[2 * u + 32], wf1 = sWih[2 * u + 33];
        float wg0 = sWih[2 * u + 64], wg1 = sWih[2 * u + 65];
        float wo0 = sWih[2 * u + 96], wo1 = sWih[2 * u + 97];
        float ip0 = bi + wi0 * x00 + wi1 * x01, ip1 = bi + wi0 * x10 + wi1 * x11;
        float fp0 = bf + wf0 * x00 + wf1 * x01, fp1 = bf + wf0 * x10 + wf1 * x11;
        float gp0 = bg + wg0 * x00 + wg1 * x01, gp1 = bg + wg0 * x10 + wg1 * x11;
        float op0 = bo + wo0 * x00 + wo1 * x01, op1 = bo + wo0 * x10 + wo1 * x11;
#pragma unroll
        for (int k = 0; k < 16; ++k) {
            float wI = sWhh[u * 16 + k];
            float wF = sWhh[(u + 16) * 16 + k];
            float wG = sWhh[(u + 32) * 16 + k];
            float wO = sWhh[(u + 48) * 16 + k];
            float h0k = h0[k], h1k = h1[k];
            ip0 += wI * h0k; ip1 += wI * h1k;
            fp0 += wF * h0k; fp1 += wF * h1k;
            gp0 += wG * h0k; gp1 += wG * h1k;
            op0 += wO * h0k; op1 += wO * h1k;
        }
        float cu0 = sigf(fp0) * c0[u] + sigf(ip0) * tanh_fast(gp0);
        float cu1 = sigf(fp1) * c1[u] + sigf(ip1) * tanh_fast(gp1);
        c0[u] = cu0; c1[u] = cu1;
        hn0[u] = sigf(op0) * tanh_fast(cu0);
        hn1[u] = sigf(op1) * tanh_fast(cu1);
    }
#pragma unroll
    for (int u = 0; u < 16; ++u) { h0[u] = hn0[u]; h1[u] = hn1[u]; }
}

template <bool EDGE>
__device__ __forceinline__ void lstm_emit(
    const float* __restrict__ h, const float* __restrict__ sD,
    float* __restrict__ outp, int e)
{
    if (EDGE) {
        float s = sD[16];
#pragma unroll
        for (int u = 0; u < 16; ++u) s += h[u] * sD[u];
        outp[e] = s;
    } else {
        float* dst = outp + (size_t)e * 16;
#pragma unroll
        for (int q = 0; q < 4; ++q)
            *(float4*)(dst + q * 4) = make_float4(h[4 * q], h[4 * q + 1], h[4 * q + 2], h[4 * q + 3]);
    }
}

// Edge: 128 threads, 2 seq/thread (grid=B/256). VGPR cap 512/3=170 -> no spill.
template <bool EDGE>
__global__ void __launch_bounds__(128, 3) lstm2_kernel(
    const float* __restrict__ seq, const int* __restrict__ lens,
    const float* __restrict__ Wih, const float* __restrict__ Whh,
    const float* __restrict__ bias,
    const float* __restrict__ dnnW, const float* __restrict__ dnnb,
    float* __restrict__ outp, int B)
{
    __shared__ float sWih[128];
    __shared__ float sWhh[1024];
    __shared__ float sB[64];
    __shared__ float sD[17];
    int tid = threadIdx.x;
    sWih[tid] = Wih[tid];
    for (int i = tid; i < 1024; i += 128) sWhh[i] = Whh[i];
    if (tid < 64) sB[tid] = bias[tid];
    if (EDGE) {
        if (tid < 16) sD[tid] = dnnW[tid];
        if (tid == 16) sD[16] = dnnb[0];
    }
    __syncthreads();
    int e0 = blockIdx.x * 256 + tid;     // seq A
    int e1 = e0 + 128;                   // seq B
    if (e0 >= B) return;
    bool v1 = e1 < B;
    int e1c = v1 ? e1 : e0;              // clamp loads; stores guarded

    const float4* sp0 = (const float4*)seq + (size_t)e0 * 8;   // 32 floats/seq
    const float4* sp1 = (const float4*)seq + (size_t)e1c * 8;
    int l0 = lens[e0] - 1;               // in [0,15]
    int l1 = lens[e1c] - 1;
    float h0[16], c0[16], h1[16], c1[16];
#pragma unroll
    for (int u = 0; u < 16; ++u) { h0[u] = 0.f; c0[u] = 0.f; h1[u] = 0.f; c1[u] = 0.f; }

    float4 q0 = sp0[0];
    float4 q1 = sp1[0];
#pragma unroll 1
    for (int i = 0; i < 8; ++i) {
        float4 n0 = sp0[(i + 1) & 7];    // prefetch (wraps on last iter; in-bounds)
        float4 n1 = sp1[(i + 1) & 7];
        lstm_step2(q0.x, q0.y, q1.x, q1.y, h0, c0, h1, c1, sWih, sWhh, sB);
        if (2 * i == l0)        lstm_emit<EDGE>(h0, sD, outp, e0);
        if (v1 && 2 * i == l1)  lstm_emit<EDGE>(h1, sD, outp, e1);
        lstm_step2(q0.z, q0.w, q1.z, q1.w, h0, c0, h1, c1, sWih, sWhh, sB);
        if (2 * i + 1 == l0)       lstm_emit<EDGE>(h0, sD, outp, e0);
        if (v1 && 2 * i + 1 == l1) lstm_emit<EDGE>(h1, sD, outp, e1);
        q0 = n0; q1 = n1;
    }
}

// Node: 128 threads, 1 seq/thread (grid=B/128).
template <bool EDGE>
__global__ void __launch_bounds__(128, 3) lstm1_kernel(
    const float* __restrict__ seq, const int* __restrict__ lens,
    const float* __restrict__ Wih, const float* __restrict__ Whh,
    const float* __restrict__ bias,
    const float* __restrict__ dnnW, const float* __restrict__ dnnb,
    float* __restrict__ outp, int B)
{
    __shared__ float sWih[128];
    __shared__ float sWhh[1024];
    __shared__ float sB[64];
    __shared__ float sD[17];
    int tid = threadIdx.x;
    sWih[tid] = Wih[tid];
    for (int i = tid; i < 1024; i += 128) sWhh[i] = Whh[i];
    if (tid < 64) sB[tid] = bias[tid];
    if (EDGE) {
        if (tid < 16) sD[tid] = dnnW[tid];
        if (tid == 16) sD[16] = dnnb[0];
    }
    __syncthreads();
    int e = blockIdx.x * 128 + tid;
    if (e >= B) return;

    const float4* sp = (const float4*)seq + (size_t)e * 8;
    int lenm1 = lens[e] - 1;
    float h[16], c[16];
#pragma unroll
    for (int u = 0; u < 16; ++u) { h[u] = 0.f; c[u] = 0.f; }

    float4 qq = sp[0];
#pragma unroll 1
    for (int i = 0; i < 8; ++i) {
        float4 qn = sp[(i + 1) & 7];
        lstm_step1(qq.x, qq.y, h, c, sWih, sWhh, sB);
        if (2 * i == lenm1)     lstm_emit<EDGE>(h, sD, outp, e);
        lstm_step1(qq.z, qq.w, h, c, sWih, sWhh, sB);
        if (2 * i + 1 == lenm1) lstm_emit<EDGE>(h, sD, outp, e);
        qq = qn;
    }
}

// ---------------- CSR build ----------------
__global__ void __launch_bounds__(256) zero_cnt_kernel(int* cnt, int n)
{
    int t = blockIdx.x * 256 + threadIdx.x;
    if (t < n) cnt[t] = 0;
}
__global__ void __launch_bounds__(256) count_kernel(const int* __restrict__ dst,
                                                    int* cnt, int E)
{
    int e = blockIdx.x * 256 + threadIdx.x;
    if (e < E) atomicAdd(&cnt[dst[e]], 1);
}
// single-block exclusive scan; also rowstart[n]=E and cursor copy.
__global__ void __launch_bounds__(256) scan_kernel(const int* __restrict__ cnt,
                                                   int* __restrict__ rs,
                                                   int* __restrict__ cur,
                                                   int n, int E)
{
    __shared__ int part[256];
    int t = threadIdx.x;
    const int CH = (n + 255) / 256;
    int base = t * CH;
    int s = 0;
    for (int i = 0; i < CH; ++i) {
        int idx = base + i;
        if (idx < n) s += cnt[idx];
    }
    part[t] = s;
    __syncthreads();
    if (t == 0) {
        int acc = 0;
        for (int i = 0; i < 256; ++i) { int v = part[i]; part[i] = acc; acc += v; }
    }
    __syncthreads();
    int run = part[t];
    for (int i = 0; i < CH; ++i) {
        int idx = base + i;
        if (idx < n) { rs[idx] = run; cur[idx] = run; run += cnt[idx]; }
    }
    if (t == 0) rs[n] = E;
}
__global__ void __launch_bounds__(256) fill_kernel(const int* __restrict__ src,
                                                   const int* __restrict__ dst,
                                                   const float* __restrict__ esc,
                                                   int* __restrict__ cur,
                                                   int* __restrict__ csrc,
                                                   float* __restrict__ cesc, int E)
{
    int e = blockIdx.x * 256 + threadIdx.x;
    if (e >= E) return;
    int pos = atomicAdd(&cur[dst[e]], 1);
    csrc[pos] = src[e];
    cesc[pos] = esc[e];
}
__global__ void __launch_bounds__(256) dinv_kernel(const int* __restrict__ cnt,
                                                   float* __restrict__ dinv, int n)
{
    int t = blockIdx.x * 256 + threadIdx.x;
    if (t < n) dinv[t] = rsqrtf((float)cnt[t] + 1.0f);
}

// --- C[n,64] = [x(240)|nodeF(16)] @ W[256,64]; 32KB static LDS, 2-phase K ---
__global__ void __launch_bounds__(256) gemmX_kernel(
    const float* __restrict__ x, const float* __restrict__ nodeF,
    const float* __restrict__ W, float* __restrict__ C, int n)
{
    __shared__ float sW[128 * 64];  // 32 KB
    int j = threadIdx.x & 63;
    int node = blockIdx.x * 4 + (threadIdx.x >> 6);
    bool valid = node < n;
    const float4* xr = (const float4*)(x + (size_t)node * 240);
    float acc = 0.f;

    for (int i = threadIdx.x; i < 128 * 64; i += 256) sW[i] = W[i];
    __syncthreads();
    if (valid) {
#pragma unroll 4
        for (int k4 = 0; k4 < 32; ++k4) {
            float4 v = xr[k4];
            const float* wr = sW + k4 * 256 + j;
            acc += v.x * wr[0] + v.y * wr[64] + v.z * wr[128] + v.w * wr[192];
        }
    }
    __syncthreads();
    for (int i = threadIdx.x; i < 128 * 64; i += 256) sW[i] = W[128 * 64 + i];
    __syncthreads();
    if (valid) {
#pragma unroll 4
        for (int k4 = 32; k4 < 60; ++k4) {
            float4 v = xr[k4];
            const float* wr = sW + (k4 - 32) * 256 + j;
            acc += v.x * wr[0] + v.y * wr[64] + v.z * wr[128] + v.w * wr[192];
        }
        const float4* nf = (const float4*)(nodeF + (size_t)node * 16);
#pragma unroll
        for (int k4 = 60; k4 < 64; ++k4) {
            float4 v = nf[k4 - 60];
            const float* wr = sW + (k4 - 32) * 256 + j;
            acc += v.x * wr[0] + v.y * wr[64] + v.z * wr[128] + v.w * wr[192];
        }
        C[(size_t)node * 64 + j] = acc;
    }
}

// ------- C[n,64] = A[n,64] @ W[64,64]; 16KB static LDS -------
__global__ void __launch_bounds__(256) gemm64_kernel(const float* __restrict__ A,
                                                     const float* __restrict__ W,
                                                     float* __restrict__ C, int n)
{
    __shared__ float sW[64 * 64];  // 16 KB
    for (int i = threadIdx.x; i < 64 * 64; i += 256) sW[i] = W[i];
    __syncthreads();
    int j = threadIdx.x & 63;
    int node = blockIdx.x * 4 + (threadIdx.x >> 6);
    if (node >= n) return;
    const float4* a4 = (const float4*)(A + (size_t)node * 64);
    float acc = 0.f;
#pragma unroll 4
    for (int k4 = 0; k4 < 16; ++k4) {
        float4 v = a4[k4];
        const float* wr = sW + k4 * 256 + j;
        acc += v.x * wr[0] + v.y * wr[64] + v.z * wr[128] + v.w * wr[192];
    }
    C[(size_t)node * 64 + j] = acc;
}

// ---------------- GAT ----------------
template <int H, int C>
__global__ void __launch_bounds__(256) alpha_kernel(const float* __restrict__ xh,
                                                    const float* __restrict__ att,
                                                    float* __restrict__ alpha, int n)
{
    int t = blockIdx.x * 256 + threadIdx.x;
    if (t >= n * H) return;
    int h = (H == 1) ? 0 : (t % H);
    int nd = (H == 1) ? t : (t / H);
    const float* row = xh + (size_t)nd * 64 + h * C;
    float s = 0.f;
#pragma unroll
    for (int c = 0; c < C; ++c) s += row[c] * att[h * C + c];
    alpha[t] = s;
}

// per (dst,h): max then sum over in-edges (CSR). Writes amax, rinv=1/sum.
template <int H>
__global__ void __launch_bounds__(256) gat_softmax_csr_kernel(
    const int* __restrict__ rs, const int* __restrict__ csrc,
    const float* __restrict__ alpha,
    float* __restrict__ amax, float* __restrict__ rinv, int n)
{
    int t = blockIdx.x * 256 + threadIdx.x;
    if (t >= n * H) return;
    int h = (H == 1) ? 0 : (t % H);
    int d = (H == 1) ? t : (t / H);
    int k0 = rs[d], k1 = rs[d + 1];
    float m = -INFINITY;
    for (int k = k0; k < k1; ++k) {
        float a = alpha[(size_t)csrc[k] * H + h];
        a = a > 0.f ? a : 0.2f * a;
        m = fmaxf(m, a);
    }
    float s = 0.f;
    for (int k = k0; k < k1; ++k) {
        float a = alpha[(size_t)csrc[k] * H + h];
        a = a > 0.f ? a : 0.2f * a;
        s += __expf(a - m);
    }
    amax[t] = m;
    rinv[t] = rcpf(s);
}

// one wave per dst node (lane = feature col). acc = xh[d]+bias + sum coef*xh[s].
template <int H, bool FILTER>
__global__ void __launch_bounds__(256) gat_gather_kernel(
    const int* __restrict__ rs, const int* __restrict__ csrc,
    const float* __restrict__ cesc,
    const float* __restrict__ xh, const float* __restrict__ alpha,
    const float* __restrict__ amax, const float* __restrict__ rinv,
    const float* __restrict__ bias, float* __restrict__ out, int n)
{
    int j = threadIdx.x & 63;
    int d = blockIdx.x * 4 + (threadIdx.x >> 6);
    if (d >= n) return;
    int h = (H == 8) ? (j >> 3) : 0;
    float m = amax[(size_t)d * H + h];
    float ri = rinv[(size_t)d * H + h];
    float acc = xh[(size_t)d * 64 + j] + bias[j];
    int k1 = rs[d + 1];
#pragma unroll 2
    for (int k = rs[d]; k < k1; ++k) {
        int s = csrc[k];
        float a = alpha[(size_t)s * H + h];
        a = a > 0.f ? a : 0.2f * a;
        float coef = __expf(a - m) * ri + cesc[k];
        acc += xh[(size_t)s * 64 + j] * coef;
    }
    if (FILTER && !__builtin_isfinite(acc)) acc = 0.f;
    out[(size_t)d * 64 + j] = acc;
}

// ---------------- GCN gather (norm + bias + leaky_relu fused) ----------------
__global__ void __launch_bounds__(256) gcn_gather_kernel(
    const int* __restrict__ rs, const int* __restrict__ csrc,
    const float* __restrict__ xw, const float* __restrict__ dinv,
    const float* __restrict__ bias, float* __restrict__ out, int n)
{
    int j = threadIdx.x & 63;
    int d = blockIdx.x * 4 + (threadIdx.x >> 6);
    if (d >= n) return;
    float di = dinv[d];
    float acc = xw[(size_t)d * 64 + j] * di * di + bias[j];
    int k1 = rs[d + 1];
#pragma unroll 2
    for (int k = rs[d]; k < k1; ++k) {
        int s = csrc[k];
        acc += xw[(size_t)s * 64 + j] * (dinv[s] * di);
    }
    out[(size_t)d * 64 + j] = acc > 0.f ? acc : 0.01f * acc;  // leaky_relu(0.01)
}

// ---------------- classifier (fused 320->32->16->4; 43.5KB static LDS) ---------
__global__ void __launch_bounds__(256) cls_kernel(
    const float* __restrict__ x, const float* __restrict__ nodeF,
    const float* __restrict__ xg,
    const float* __restrict__ W1, const float* __restrict__ b1,
    const float* __restrict__ W2, const float* __restrict__ b2,
    const float* __restrict__ W3, const float* __restrict__ b3,
    float* __restrict__ outp, int n)
{
    __shared__ float sW1[320 * 32];
    __shared__ float sW2[32 * 16];
    __shared__ float sW3[16 * 4];
    __shared__ float sb1[32], sb2[16], sb3[4];
    int tid = threadIdx.x;
    for (int i = tid; i < 320 * 32; i += 256) sW1[i] = W1[i];
    for (int i = tid; i < 512; i += 256) sW2[i] = W2[i];
    if (tid < 64) sW3[tid] = W3[tid];
    if (tid < 32) sb1[tid] = b1[tid];
    if (tid < 16) sb2[tid] = b2[tid];
    if (tid < 4)  sb3[tid] = b3[tid];
    __syncthreads();
    int nd = blockIdx.x * 256 + tid;
    if (nd >= n) return;

    float a1[32];
#pragma unroll
    for (int j = 0; j < 32; ++j) a1[j] = sb1[j];
    const float4* xr = (const float4*)(x + (size_t)nd * 240);
#pragma unroll 1
    for (int k4 = 0; k4 < 60; ++k4) {
        float4 v = xr[k4];
        const float* wr = sW1 + k4 * 128;
#pragma unroll
        for (int j = 0; j < 32; ++j)
            a1[j] += v.x * wr[j] + v.y * wr[32 + j] + v.z * wr[64 + j] + v.w * wr[96 + j];
    }
    const float4* nf = (const float4*)(nodeF + (size_t)nd * 16);
#pragma unroll 1
    for (int k4 = 60; k4 < 64; ++k4) {
        float4 v = nf[k4 - 60];
        const float* wr = sW1 + k4 * 128;
#pragma unroll
        for (int j = 0; j < 32; ++j)
            a1[j] += v.x * wr[j] + v.y * wr[32 + j] + v.z * wr[64 + j] + v.w * wr[96 + j];
    }
    const float4* p2 = (const float4*)(xg + (size_t)nd * 64);
#pragma unroll 1
    for (int k4 = 0; k4 < 16; ++k4) {
        float4 v = p2[k4];
        const float* wr = sW1 + 8192 + k4 * 128;  // rows 256 + 4*k4
#pragma unroll
        for (int j = 0; j < 32; ++j)
            a1[j] += v.x * wr[j] + v.y * wr[32 + j] + v.z * wr[64 + j] + v.w * wr[96 + j];
    }
#pragma unroll
    for (int j = 0; j < 32; ++j) { float v = a1[j]; a1[j] = v > 0.f ? v : 0.01f * v; }

    float a2[16];
#pragma unroll
    for (int j = 0; j < 16; ++j) a2[j] = sb2[j];
#pragma unroll
    for (int k = 0; k < 32; ++k) {
        float v = a1[k];
        const float* wr = sW2 + k * 16;
#pragma unroll
        for (int j = 0; j < 16; ++j) a2[j] += v * wr[j];
    }
#pragma unroll
    for (int j = 0; j < 16; ++j) { float v = a2[j]; a2[j] = v > 0.f ? v : 0.01f * v; }

    float a3[4] = {sb3[0], sb3[1], sb3[2], sb3[3]};
#pragma unroll
    for (int k = 0; k < 16; ++k) {
        float v = a2[k];
        const float* wr = sW3 + k * 4;
        a3[0] += v * wr[0]; a3[1] += v * wr[1]; a3[2] += v * wr[2]; a3[3] += v * wr[3];
    }
    float4 o = make_float4(a3[0], a3[1], a3[2], a3[3]);
    *(float4*)(outp + (size_t)nd * 4) = o;
}

// ---------------- launcher ----------------
static inline unsigned nblk(size_t t) { return (unsigned)((t + 255) / 256); }

extern "C" void kernel_launch(void* const* d_in, const int* in_sizes, int n_in,
                              void* d_out, int out_size, void* d_ws, size_t ws_size,
                              hipStream_t stream)
{
    const float* x     = (const float*)d_in[0];
    const float* eseq  = (const float*)d_in[1];
    const float* nseq  = (const float*)d_in[2];
    const float* Wih   = (const float*)d_in[3];
    const float* Whh   = (const float*)d_in[4];
    const float* lb    = (const float*)d_in[5];
    const float* dnnW  = (const float*)d_in[6];
    const float* dnnb  = (const float*)d_in[7];
    const float* g1W   = (const float*)d_in[8];
    const float* g1att = (const float*)d_in[9];
    const float* g1b   = (const float*)d_in[10];
    const float* g2W   = (const float*)d_in[11];
    const float* g2att = (const float*)d_in[12];
    const float* g2b   = (const float*)d_in[13];
    const float* gc1W  = (const float*)d_in[14];
    const float* gc1b  = (const float*)d_in[15];
    const float* gc2W  = (const float*)d_in[16];
    const float* gc2b  = (const float*)d_in[17];
    const float* c1W   = (const float*)d_in[18];
    const float* c1b   = (const float*)d_in[19];
    const float* c2W   = (const float*)d_in[20];
    const float* c2b   = (const float*)d_in[21];
    const float* c3W   = (const float*)d_in[22];
    const float* c3b   = (const float*)d_in[23];
    const int* eidx  = (const int*)d_in[24];
    const int* elen  = (const int*)d_in[25];
    const int* nlen  = (const int*)d_in[26];

    const int N = NN;
    const int E = EE;
    const int* srcp = eidx;
    const int* dstp = eidx + E;

    // device-global scratch
    float *nodeF, *esc, *P1, *P2, *alpha, *amax, *rinv, *dinv, *cesc;
    int *cnt, *rs, *cur, *csrc;
    hipGetSymbolAddress((void**)&nodeF, HIP_SYMBOL(g_nodeF));
    hipGetSymbolAddress((void**)&esc,   HIP_SYMBOL(g_esc));
    hipGetSymbolAddress((void**)&P1,    HIP_SYMBOL(g_P1));
    hipGetSymbolAddress((void**)&P2,    HIP_SYMBOL(g_P2));
    hipGetSymbolAddress((void**)&alpha, HIP_SYMBOL(g_alpha));
    hipGetSymbolAddress((void**)&amax,  HIP_SYMBOL(g_amax));
    hipGetSymbolAddress((void**)&rinv,  HIP_SYMBOL(g_rinv));
    hipGetSymbolAddress((void**)&dinv,  HIP_SYMBOL(g_dinv));
    hipGetSymbolAddress((void**)&cnt,   HIP_SYMBOL(g_cnt));
    hipGetSymbolAddress((void**)&rs,    HIP_SYMBOL(g_rs));
    hipGetSymbolAddress((void**)&cur,   HIP_SYMBOL(g_cur));
    hipGetSymbolAddress((void**)&csrc,  HIP_SYMBOL(g_csrc));
    hipGetSymbolAddress((void**)&cesc,  HIP_SYMBOL(g_cesc));

    float* out0   = (float*)d_out;             // [N,4]
    float* outGcn = out0 + (size_t)N * 4;      // [N,64]
    float* outGat = outGcn + (size_t)N * 64;   // [N,64]

    // ---- temporal branches ----
    lstm1_kernel<false><<<(N + 127) / 128, 128, 0, stream>>>(nseq, nlen, Wih, Whh, lb, dnnW, dnnb, nodeF, N);
    lstm2_kernel<true><<<(E + 255) / 256, 128, 0, stream>>>(eseq, elen, Wih, Whh, lb, dnnW, dnnb, esc, E);

    // ---- CSR build (graph fixed per launch; also yields GCN degrees) ----
    zero_cnt_kernel<<<nblk(N), 256, 0, stream>>>(cnt, N);
    count_kernel<<<nblk(E), 256, 0, stream>>>(dstp, cnt, E);
    scan_kernel<<<1, 256, 0, stream>>>(cnt, rs, cur, N, E);
    fill_kernel<<<nblk(E), 256, 0, stream>>>(srcp, dstp, esc, cur, csrc, cesc, E);
    dinv_kernel<<<nblk(N), 256, 0, stream>>>(cnt, dinv, N);

    // ---- GAT layer 1 (H=8, C=8): P1 = xh1, P2 = gat1 out ----
    gemmX_kernel<<<(N + 3) / 4, 256, 0, stream>>>(x, nodeF, g1W, P1, N);
    alpha_kernel<8, 8><<<nblk((size_t)N * 8), 256, 0, stream>>>(P1, g1att, alpha, N);
    gat_softmax_csr_kernel<8><<<nblk((size_t)N * 8), 256, 0, stream>>>(rs, csrc, alpha, amax, rinv, N);
    gat_gather_kernel<8, false><<<(N + 3) / 4, 256, 0, stream>>>(
        rs, csrc, cesc, P1, alpha, amax, rinv, g1b, P2, N);

    // ---- GAT layer 2 (H=1, C=64): P1 = xh2, output -> outGat ----
    gemm64_kernel<<<(N + 3) / 4, 256, 0, stream>>>(P2, g2W, P1, N);
    alpha_kernel<1, 64><<<nblk(N), 256, 0, stream>>>(P1, g2att, alpha, N);
    gat_softmax_csr_kernel<1><<<nblk(N), 256, 0, stream>>>(rs, csrc, alpha, amax, rinv, N);
    gat_gather_kernel<1, true><<<(N + 3) / 4, 256, 0, stream>>>(
        rs, csrc, cesc, P1, alpha, amax, rinv, g2b, outGat, N);

    // ---- GCN layer 1: P1 = xw1, P2 = lrelu(gcn1) ----
    gemmX_kernel<<<(N + 3) / 4, 256, 0, stream>>>(x, nodeF, gc1W, P1, N);
    gcn_gather_kernel<<<(N + 3) / 4, 256, 0, stream>>>(rs, csrc, P1, dinv, gc1b, P2, N);

    // ---- GCN layer 2: P1 = xw2, output -> outGcn (x_gcn, lrelu fused) ----
    gemm64_kernel<<<(N + 3) / 4, 256, 0, stream>>>(P2, gc2W, P1, N);
    gcn_gather_kernel<<<(N + 3) / 4, 256, 0, stream>>>(rs, csrc, P1, dinv, gc2b, outGcn, N);

    // ---- classifier (reads x_gcn from d_out) ----
    cls_kernel<<<nblk(N), 256, 0, stream>>>(x, nodeF, outGcn, c1W, c1b, c2W, c2b, c3W, c3b, out0, N);
}